// Round 2
// baseline (6706.030 us; speedup 1.0000x reference)
//
#include <hip/hip_runtime.h>

typedef unsigned short u16;
typedef unsigned int   u32;

__device__ __forceinline__ float u2f(u32 u){
  union { u32 i; float f; } v; v.i = u << 16; return v.f;
}
__device__ __forceinline__ u16 f2bu(float f){
  union { float f; u32 i; } v; v.f = f;
  u32 i = v.i;
  i += 0x7fffu + ((i >> 16) & 1u);   // round-to-nearest-even
  return (u16)(i >> 16);
}
__device__ __forceinline__ float sigm(float x){ return 1.0f/(1.0f + expf(-x)); }

// generic scalar load: bf16 bits or f32, selected by uniform flag
__device__ __forceinline__ float ldf(const void* p, size_t i, int bf){
  return bf ? u2f(((const u16*)p)[i]) : ((const float*)p)[i];
}

// ---------------------------------------------------------------------------
// Kernel 0: dtype detector. If input is bf16, the low u16 half of each u32 of
// norm_vector (N(0,1) data) is a valid bf16 with exponent ~[110,130]; if f32,
// low halves are uniform mantissa bits (exponent-sane only ~16% of the time).
// ---------------------------------------------------------------------------
__global__ __launch_bounds__(64) void k_detect(const u32* __restrict__ nv,
                                               int* __restrict__ flag)
{
  int i = threadIdx.x;
  u32 w = nv[i];
  u32 e = (w >> 7) & 0xffu;
  bool sane = (e >= 100u && e <= 140u);
  unsigned long long m = __ballot(sane);
  if (i == 0) *flag = (__popcll(m) >= 40) ? 1 : 0;
}

// ---------------------------------------------------------------------------
// Kernel 1: neighbor encoder. One block per sequence n = (f*2+s)*256 + b.
// ---------------------------------------------------------------------------
__global__ __launch_bounds__(256) void k_neighbor(
    const int* __restrict__ left, const int* __restrict__ right,
    const void* __restrict__ emb,
    const void* __restrict__ gcnw, const void* __restrict__ gcnwb, const void* __restrict__ gcnb,
    const void* __restrict__ attnw, const void* __restrict__ attnwb,
    const void* __restrict__ gatew, const void* __restrict__ gatewb, const void* __restrict__ gateb,
    const int* __restrict__ flag,
    float* __restrict__ X0)
{
  __shared__ __align__(16) u16 out_s[200][104];
  __shared__ __align__(16) u16 cat_s[16][200];
  __shared__ float logit_s[256];
  __shared__ float red_s[256];
  __shared__ float attnw_s[100], gatew_s[100], gbias_s[100], oa_s[100];
  __shared__ int c1_s[16], c2_s[16];

  const int bf = *flag;
  const int tid = threadIdx.x;
  const int n = blockIdx.x;
  const int b = n % 256;
  const int fs = n / 256;
  const int s = fs & 1;
  const int f = fs >> 1;
  const int* conn = (s == 0 ? left : right) + (size_t)(f*256 + b)*200*3;

  const u16*   emb16 = (const u16*)emb;
  const float* emb32 = (const float*)emb;

  if (tid < 100){
    attnw_s[tid] = ldf(attnw, tid, bf);
    gatew_s[tid] = ldf(gatew, tid, bf);
    gbias_s[tid] = ldf(gcnwb, tid, bf) + ldf(gcnb, tid, bf);
  }
  __syncthreads();

  for (int t0 = 0; t0 < 200; t0 += 16){
    if (tid < 16){
      int m = t0 + tid;
      if (m < 200){ c1_s[tid] = conn[m*3+1]; c2_s[tid] = conn[m*3+2]; }
    }
    __syncthreads();
    for (int e = tid; e < 16*200; e += 256){
      int mi = e / 200, k = e - mi*200;
      int m = t0 + mi;
      if (m < 200){
        int col = (k < 100) ? c1_s[mi] : c2_s[mi];
        int kk  = (k < 100) ? k : (k - 100);
        size_t idx = (size_t)col*100 + kk;
        cat_s[mi][k] = bf ? emb16[idx] : f2bu(emb32[idx]);
      }
    }
    __syncthreads();
    for (int e = tid; e < 16*100; e += 256){
      int mi = e / 100, d = e - mi*100;
      int m = t0 + mi;
      if (m < 200){
        float acc = gbias_s[d];
        const u16* crow = cat_s[mi];
        if (bf){
          const u16* wrow = (const u16*)gcnw + d*200;
          #pragma unroll 5
          for (int k = 0; k < 200; k += 4){
            uint2 wv = *(const uint2*)(wrow + k);
            uint2 cv = *(const uint2*)(crow + k);
            acc += u2f(cv.x & 0xffffu) * u2f(wv.x & 0xffffu);
            acc += u2f(cv.x >> 16)     * u2f(wv.x >> 16);
            acc += u2f(cv.y & 0xffffu) * u2f(wv.y & 0xffffu);
            acc += u2f(cv.y >> 16)     * u2f(wv.y >> 16);
          }
        } else {
          const float* wrow = (const float*)gcnw + d*200;
          #pragma unroll 5
          for (int k = 0; k < 200; k += 4){
            float4 wv = *(const float4*)(wrow + k);
            uint2 cv = *(const uint2*)(crow + k);
            acc += u2f(cv.x & 0xffffu) * wv.x;
            acc += u2f(cv.x >> 16)     * wv.y;
            acc += u2f(cv.y & 0xffffu) * wv.z;
            acc += u2f(cv.y >> 16)     * wv.w;
          }
        }
        float v = acc > 0.0f ? acc : 0.01f*acc;
        out_s[m][d] = f2bu(v);
      }
    }
    __syncthreads();
  }

  if (tid < 200){
    float acc = ldf(attnwb, 0, bf);
    for (int d = 0; d < 100; ++d) acc += u2f(out_s[tid][d]) * attnw_s[d];
    logit_s[tid] = acc;
  }
  __syncthreads();
  red_s[tid] = (tid < 200) ? logit_s[tid] : -3.0e38f;
  __syncthreads();
  for (int off = 128; off > 0; off >>= 1){
    if (tid < off) red_s[tid] = fmaxf(red_s[tid], red_s[tid+off]);
    __syncthreads();
  }
  float mx = red_s[0];
  __syncthreads();
  float ev = 0.0f;
  if (tid < 200){ ev = expf(logit_s[tid] - mx); logit_s[tid] = ev; }
  red_s[tid] = ev;
  __syncthreads();
  for (int off = 128; off > 0; off >>= 1){
    if (tid < off) red_s[tid] += red_s[tid+off];
    __syncthreads();
  }
  float S = red_s[0];
  __syncthreads();

  if (tid < 100){
    float acc = 0.0f;
    for (int m = 0; m < 200; ++m) acc += u2f(out_s[m][tid]) * logit_s[m];
    oa_s[tid] = acc / S;
  }
  __syncthreads();
  if (tid == 0){
    float g = ldf(gatewb, 0, bf) + ldf(gateb, 0, bf);
    for (int d = 0; d < 100; ++d) g += oa_s[d] * gatew_s[d];
    red_s[0] = sigm(g);
  }
  __syncthreads();
  float gate = red_s[0];
  if (tid < 100){
    int c0 = conn[0];
    float self = ldf(emb, (size_t)c0*100 + tid, bf);
    X0[((size_t)f*256 + b)*200 + s*100 + tid] = oa_s[tid]*gate + self*(1.0f - gate);
  }
}

// ---------------------------------------------------------------------------
// Kernel 2: out[r][j] = b1[j+bOff]+b2[j+bOff] + sum_k A[r][k]*W[(wOff/K+j)][k]
// W/biases addressed with ELEMENT offsets (dtype-agnostic).
// ---------------------------------------------------------------------------
__global__ __launch_bounds__(256) void k_gemm(
    const float* __restrict__ A, const void* __restrict__ W, size_t wEl,
    const void* __restrict__ b1, const void* __restrict__ b2, size_t bEl,
    const int* __restrict__ flag,
    float* __restrict__ out, int K, int C)
{
  extern __shared__ float a_s[];
  const int bf = *flag;
  const int tid = threadIdx.x;
  const int r = blockIdx.y;
  const float* a = A + (size_t)r*K;
  for (int k = tid; k < K; k += 256) a_s[k] = a[k];
  __syncthreads();
  const int j = blockIdx.x*256 + tid;
  if (j >= C) return;
  float acc = 0.0f;
  if (b1) acc += ldf(b1, bEl + j, bf);
  if (b2) acc += ldf(b2, bEl + j, bf);
  if (bf){
    const u16* w = (const u16*)W + wEl + (size_t)j*K;
    for (int k = 0; k < K; k += 4){
      uint2 wv = *(const uint2*)(w + k);
      acc += a_s[k]   * u2f(wv.x & 0xffffu);
      acc += a_s[k+1] * u2f(wv.x >> 16);
      acc += a_s[k+2] * u2f(wv.y & 0xffffu);
      acc += a_s[k+3] * u2f(wv.y >> 16);
    }
  } else {
    const float* w = (const float*)W + wEl + (size_t)j*K;
    for (int k = 0; k < K; k += 4){
      float4 wv = *(const float4*)(w + k);
      acc += a_s[k]*wv.x + a_s[k+1]*wv.y + a_s[k+2]*wv.z + a_s[k+3]*wv.w;
    }
  }
  out[(size_t)r*C + j] = acc;
}

// ---------------------------------------------------------------------------
// Kernel 3: LSTM recurrent gate GEMM, one timestep, both directions.
// ---------------------------------------------------------------------------
__global__ __launch_bounds__(256) void k_gates(
    const float* __restrict__ G, const float* __restrict__ HC,
    const void* __restrict__ Whh, const int* __restrict__ flag,
    float* __restrict__ GT, int s)
{
  __shared__ float h_s[450];
  const int bf = *flag;
  const int tid = threadIdx.x;
  const int dir = blockIdx.z;
  const int b = blockIdx.y;
  const int t_eff = dir ? (4 - s) : s;
  const float* h = HC + ((size_t)dir*256 + b)*450;
  for (int k = tid; k < 450; k += 256) h_s[k] = h[k];
  __syncthreads();
  const int j = blockIdx.x*256 + tid;
  if (j >= 1800) return;
  float acc = G[(((size_t)dir*5 + t_eff)*256 + b)*1800 + j];
  if (bf){
    const u16* w = (const u16*)Whh + ((size_t)dir*1800 + j)*450;
    for (int k = 0; k < 450; k += 2){
      u32 wv = *(const u32*)(w + k);
      acc += h_s[k]   * u2f(wv & 0xffffu);
      acc += h_s[k+1] * u2f(wv >> 16);
    }
  } else {
    const float* w = (const float*)Whh + ((size_t)dir*1800 + j)*450;
    for (int k = 0; k < 450; k += 2){
      float2 wv = *(const float2*)(w + k);
      acc += h_s[k]*wv.x + h_s[k+1]*wv.y;
    }
  }
  GT[((size_t)dir*256 + b)*1800 + j] = acc;
}

// ---------------------------------------------------------------------------
// Kernel 4: LSTM cell pointwise update.
// ---------------------------------------------------------------------------
__global__ __launch_bounds__(256) void k_cell(
    const float* __restrict__ GT, float* __restrict__ HC,
    float* __restrict__ Y, float* __restrict__ HF, int s, int layer)
{
  int idx = blockIdx.x*256 + threadIdx.x;
  if (idx >= 2*256*450) return;
  int k = idx % 450;
  int rb = idx / 450;
  int b = rb % 256;
  int dir = rb / 256;
  int t_eff = dir ? (4 - s) : s;
  const float* g = GT + ((size_t)dir*256 + b)*1800;
  float gi = g[k], gf = g[450+k], gg = g[900+k], go = g[1350+k];
  float* hp = HC + ((size_t)dir*256 + b)*450 + k;
  float* cp = HC + ((size_t)(2+dir)*256 + b)*450 + k;
  float c = sigm(gf)*(*cp) + sigm(gi)*tanhf(gg);
  float hv = sigm(go)*tanhf(c);
  *cp = c; *hp = hv;
  Y[((size_t)t_eff*256 + b)*900 + dir*450 + k] = hv;
  HF[((size_t)(layer*2+dir)*256 + b)*450 + k] = hv;
}

// ---------------------------------------------------------------------------
// Kernel 5: attention over timesteps + context. hidden uses the reference's
// cross-batch reshape quirk: hidden[b][h][l] = HF_flat[b*1800 + h*2 + l].
// ---------------------------------------------------------------------------
__global__ __launch_bounds__(256) void k_attn(
    const float* __restrict__ Y1, const float* __restrict__ HF,
    float* __restrict__ CTX)
{
  __shared__ float red[256];
  __shared__ float sc[10];
  __shared__ float aw[10];
  int b = blockIdx.x, tid = threadIdx.x;
  for (int p = 0; p < 10; ++p){
    int t = p >> 1, l = p & 1;
    float a = 0.0f;
    for (int h = tid; h < 900; h += 256)
      a += Y1[((size_t)t*256 + b)*900 + h] * HF[(size_t)b*1800 + h*2 + l];
    red[tid] = a; __syncthreads();
    for (int off = 128; off > 0; off >>= 1){
      if (tid < off) red[tid] += red[tid+off];
      __syncthreads();
    }
    if (tid == 0) sc[p] = red[0];
    __syncthreads();
  }
  if (tid < 2){
    int l = tid;
    float mxv = -3.0e38f;
    for (int t = 0; t < 5; ++t) mxv = fmaxf(mxv, sc[t*2+l]);
    float e[5], sum = 0.0f;
    for (int t = 0; t < 5; ++t){ e[t] = expf(sc[t*2+l]-mxv); sum += e[t]; }
    for (int t = 0; t < 5; ++t) aw[t*2+l] = e[t]/sum;
  }
  __syncthreads();
  for (int h = tid; h < 900; h += 256){
    float v0 = 0.0f, v1 = 0.0f;
    for (int t = 0; t < 5; ++t){
      float y = Y1[((size_t)t*256 + b)*900 + h];
      v0 += y*aw[t*2+0]; v1 += y*aw[t*2+1];
    }
    CTX[(size_t)b*1800 + h*2 + 0] = v0;
    CTX[(size_t)b*1800 + h*2 + 1] = v1;
  }
}

__device__ __forceinline__ float bred128(float v, float* red, int tid){
  red[tid] = v; __syncthreads();
  for (int off = 64; off > 0; off >>= 1){
    if (tid < off) red[tid] += red[tid+off];
    __syncthreads();
  }
  float r = red[0]; __syncthreads();
  return r;
}

// ---------------------------------------------------------------------------
// Kernel 6: analytic meta-gradient -> rel_q, norm_q. One block per b.
// ---------------------------------------------------------------------------
__global__ __launch_bounds__(128) void k_grad(
    const void* __restrict__ sup, const void* __restrict__ supn,
    const void* __restrict__ normv, const float* __restrict__ REL,
    const int* __restrict__ flag,
    float* __restrict__ RELQ, float* __restrict__ NORMQ)
{
  __shared__ float red[128];
  __shared__ float nv[100], rl[100], acc[100];
  const int bf = *flag;
  int b = blockIdx.x, tid = threadIdx.x;
  if (tid < 100){
    nv[tid] = ldf(normv, b*100+tid, bf);
    rl[tid] = REL[b*100+tid];
    acc[tid] = 0.0f;
  }
  __syncthreads();
  float nvd = (tid < 100) ? nv[tid] : 0.0f;
  float rld = (tid < 100) ? rl[tid] : 0.0f;
  for (int j = 0; j < 5; ++j){
    float h1=0.f,t1=0.f,h2=0.f,t2=0.f;
    if (tid < 100){
      size_t base = (size_t)(b*5+j)*200;
      h1 = ldf(sup,  base + tid, bf);  t1 = ldf(sup,  base + 100 + tid, bf);
      h2 = ldf(supn, base + tid, bf);  t2 = ldf(supn, base + 100 + tid, bf);
    }
    float hd1 = bred128(h1*nvd, red, tid);
    float td1 = bred128(t1*nvd, red, tid);
    float hd2 = bred128(h2*nvd, red, tid);
    float td2 = bred128(t2*nvd, red, tid);
    float upd = (h1 - hd1*nvd) + rld - (t1 - td1*nvd);
    float und = (h2 - hd2*nvd) + rld - (t2 - td2*nvd);
    if (tid >= 100){ upd = 0.0f; und = 0.0f; }
    float np2 = bred128(upd*upd, red, tid);
    float nn2 = bred128(und*und, red, tid);
    float p = -sqrtf(np2), nsc = -sqrtf(nn2);
    if ((1.0f - (p - nsc) > 0.0f) && tid < 100)
      acc[tid] += upd/sqrtf(np2) - und/sqrtf(nn2);
  }
  __syncthreads();
  if (tid < 100){
    float g = acc[tid] * (1.0f/1280.0f);
    RELQ[b*100+tid]  = rl[tid] - 5.0f*g;
    NORMQ[b*100+tid] = nv[tid] - 5.0f*g;
  }
}

// ---------------------------------------------------------------------------
// Kernel 7: final scores (10 query + 512 negative per b). Output per flag.
// ---------------------------------------------------------------------------
__global__ __launch_bounds__(192) void k_score(
    const void* __restrict__ query, const void* __restrict__ neg,
    const float* __restrict__ RELQ, const float* __restrict__ NORMQ,
    const int* __restrict__ flag, void* __restrict__ out)
{
  __shared__ float nq[100], rq[100];
  const int bf = *flag;
  int b = blockIdx.x, tid = threadIdx.x;
  if (tid < 100){ nq[tid] = NORMQ[b*100+tid]; rq[tid] = RELQ[b*100+tid]; }
  __syncthreads();
  int qi = blockIdx.y*192 + tid;
  if (qi >= 522) return;
  const void* src = (qi < 10) ? query : neg;
  size_t row = (qi < 10) ? ((size_t)b*10 + qi) : ((size_t)b*512 + qi - 10);
  size_t base = row*200;
  float hd = 0.0f, td = 0.0f;
  for (int d = 0; d < 100; ++d){
    hd += ldf(src, base + d, bf)       * nq[d];
    td += ldf(src, base + 100 + d, bf) * nq[d];
  }
  float s2 = 0.0f;
  for (int d = 0; d < 100; ++d){
    float u = (ldf(src, base + d, bf) - hd*nq[d]) + rq[d]
            - (ldf(src, base + 100 + d, bf) - td*nq[d]);
    s2 += u*u;
  }
  float sc = -sqrtf(s2);
  size_t oi = (qi < 10) ? ((size_t)b*10 + qi) : (2560 + (size_t)b*512 + (qi - 10));
  if (bf) ((u16*)out)[oi] = f2bu(sc);
  else    ((float*)out)[oi] = sc;
}

// ---------------------------------------------------------------------------
extern "C" void kernel_launch(void* const* d_in, const int* in_sizes, int n_in,
                              void* d_out, int out_size, void* d_ws, size_t ws_size,
                              hipStream_t stream)
{
  const void* support = d_in[0];
  const void* supneg  = d_in[1];
  const void* query   = d_in[2];
  const void* negat   = d_in[3];
  const void* normv   = d_in[4];
  const int* left     = (const int*)d_in[5];
  const int* right    = (const int*)d_in[6];
  const void* emb     = d_in[7];
  const void* gcnw    = d_in[8];
  const void* gcnwb   = d_in[9];
  const void* gcnb    = d_in[10];
  const void* attnw   = d_in[11];
  const void* attnwb  = d_in[12];
  const void* gatew   = d_in[13];
  const void* gatewb  = d_in[14];
  const void* gateb   = d_in[15];
  const void* Wih0    = d_in[16];
  const void* Whh0    = d_in[17];
  const void* bih0    = d_in[18];
  const void* bhh0    = d_in[19];
  const void* Wih1    = d_in[20];
  const void* Whh1    = d_in[21];
  const void* bih1    = d_in[22];
  const void* bhh1    = d_in[23];
  const void* outw    = d_in[24];
  const void* outb    = d_in[25];

  int*   dflag = (int*)d_ws;
  float* ws    = (float*)d_ws + 16;
  float* X0   = ws;                  // 5*256*200      = 256000
  float* G    = X0 + 256000;         // 2*5*256*1800   = 4608000
  float* Y0   = G + 4608000;         // 5*256*900      = 1152000
  float* Y1   = Y0 + 1152000;        // 1152000
  float* HF   = Y1 + 1152000;        // 4*256*450      = 460800
  float* HC   = HF + 460800;         // h,c (2 dirs)   = 460800
  float* CTX  = HC + 460800;         // 256*1800       = 460800
  float* RELb = CTX + 460800;        // 25600
  float* RELQ = RELb + 25600;
  float* NORMQ= RELQ + 25600;
  float* GT   = NORMQ + 25600;       // 2*256*1800     = 921600

  k_detect<<<1, 64, 0, stream>>>((const u32*)normv, dflag);

  k_neighbor<<<2560, 256, 0, stream>>>(left, right, emb, gcnw, gcnwb, gcnb,
                                       attnw, attnwb, gatew, gatewb, gateb,
                                       dflag, X0);
  hipMemsetAsync(HC, 0, 460800*sizeof(float), stream);
  k_gemm<<<dim3(8,1280), 256, 200*4, stream>>>(X0, Wih0, 0,      bih0, bhh0, 0,
                                               dflag, G,           200, 1800);
  k_gemm<<<dim3(8,1280), 256, 200*4, stream>>>(X0, Wih0, 360000, bih0, bhh0, 1800,
                                               dflag, G + 2304000, 200, 1800);
  for (int s = 0; s < 5; ++s){
    k_gates<<<dim3(8,256,2), 256, 0, stream>>>(G, HC, Whh0, dflag, GT, s);
    k_cell<<<900, 256, 0, stream>>>(GT, HC, Y0, HF, s, 0);
  }
  hipMemsetAsync(HC, 0, 460800*sizeof(float), stream);
  k_gemm<<<dim3(8,1280), 256, 900*4, stream>>>(Y0, Wih1, 0,       bih1, bhh1, 0,
                                               dflag, G,           900, 1800);
  k_gemm<<<dim3(8,1280), 256, 900*4, stream>>>(Y0, Wih1, 1620000, bih1, bhh1, 1800,
                                               dflag, G + 2304000, 900, 1800);
  for (int s = 0; s < 5; ++s){
    k_gates<<<dim3(8,256,2), 256, 0, stream>>>(G, HC, Whh1, dflag, GT, s);
    k_cell<<<900, 256, 0, stream>>>(GT, HC, Y1, HF, s, 1);
  }
  k_attn<<<256, 256, 0, stream>>>(Y1, HF, CTX);
  k_gemm<<<dim3(1,256), 256, 1800*4, stream>>>(CTX, outw, 0, outb, nullptr, 0,
                                               dflag, RELb, 1800, 100);
  k_grad<<<256, 128, 0, stream>>>(support, supneg, normv, RELb, dflag, RELQ, NORMQ);
  k_score<<<dim3(256,3), 192, 0, stream>>>(query, negat, RELQ, NORMQ, dflag, d_out);
}

// Round 3
// 4380.421 us; speedup vs baseline: 1.5309x; 1.5309x over previous
//
#include <hip/hip_runtime.h>

typedef unsigned short u16;
typedef unsigned int   u32;
typedef __attribute__((ext_vector_type(8))) short short8;
typedef __attribute__((ext_vector_type(4))) float f32x4;

__device__ __forceinline__ float u2f(u32 u){
  union { u32 i; float f; } v; v.i = u << 16; return v.f;
}
__device__ __forceinline__ u16 f2bu(float f){
  union { float f; u32 i; } v; v.f = f;
  u32 i = v.i;
  i += 0x7fffu + ((i >> 16) & 1u);   // round-to-nearest-even
  return (u16)(i >> 16);
}
__device__ __forceinline__ float sigm(float x){ return 1.0f/(1.0f + expf(-x)); }

// generic scalar load: bf16 bits or f32, selected by uniform flag
__device__ __forceinline__ float ldf(const void* p, size_t i, int bf){
  return bf ? u2f(((const u16*)p)[i]) : ((const float*)p)[i];
}

// ---------------------------------------------------------------------------
// Kernel 0: dtype detector (bf16 vs f32 device buffers). See round-2 notes.
// ---------------------------------------------------------------------------
__global__ __launch_bounds__(64) void k_detect(const u32* __restrict__ nv,
                                               int* __restrict__ flag)
{
  int i = threadIdx.x;
  u32 w = nv[i];
  u32 e = (w >> 7) & 0xffu;
  bool sane = (e >= 100u && e <= 140u);
  unsigned long long m = __ballot(sane);
  if (i == 0) *flag = (__popcll(m) >= 40) ? 1 : 0;
}

// ---------------------------------------------------------------------------
// Kernel 1: neighbor encoder, MFMA version. One block (256 thr) per sequence
// n = (f*2+s)*256 + b.  GEMM: out[200][100] = cat[200][200] @ w^T, K-chunked
// by 32 with fused gather; then bias+leaky -> LDS; then attention+gate -> X0.
// ---------------------------------------------------------------------------
__global__ __launch_bounds__(256) void k_gcn(
    const int* __restrict__ left, const int* __restrict__ right,
    const void* __restrict__ emb,
    const void* __restrict__ gcnw, const void* __restrict__ gcnwb, const void* __restrict__ gcnb,
    const void* __restrict__ attnw, const void* __restrict__ attnwb,
    const void* __restrict__ gatew, const void* __restrict__ gatewb, const void* __restrict__ gateb,
    const int* __restrict__ flag,
    float* __restrict__ X0)
{
  // staging region (A:[208][40] u16 = 16640B, B:[112][40] u16 = 8960B) unioned
  // with out_s [200][104] u16 = 41600B (used only after the K-loop).
  __shared__ __align__(16) char smem[41600];
  __shared__ int c1_s[200], c2_s[200];
  __shared__ float logit_s[256], red_s[256];
  __shared__ float attnw_s[100], gatew_s[100], bias_s[100], oa_s[100];

  u16* As    = (u16*)smem;              // [208][40]
  u16* Bs    = (u16*)(smem + 16640);    // [112][40]
  u16* out_s = (u16*)smem;              // [200][104] after K-loop

  const int bf  = *flag;
  const int tid = threadIdx.x;
  const int n   = blockIdx.x;
  const int b   = n & 255;
  const int fs  = n >> 8;
  const int s   = fs & 1;
  const int f   = fs >> 1;
  const int* conn = (s == 0 ? left : right) + (size_t)(f*256 + b)*600;

  const u16*   emb16 = (const u16*)emb;
  const float* emb32 = (const float*)emb;
  const u16*   w16   = (const u16*)gcnw;
  const float* w32   = (const float*)gcnw;

  if (tid < 200){ c1_s[tid] = conn[tid*3+1]; c2_s[tid] = conn[tid*3+2]; }
  if (tid < 100){
    attnw_s[tid] = ldf(attnw, tid, bf);
    gatew_s[tid] = ldf(gatew, tid, bf);
    bias_s[tid]  = ldf(gcnwb, tid, bf) + ldf(gcnb, tid, bf);
  }
  __syncthreads();

  const int wid  = tid >> 6, lane = tid & 63, ln = lane & 15, quad = lane >> 4;
  // m-tile strips per wave: {0..3},{4..6},{7..9},{10..12}
  const int mt0 = (wid == 0) ? 0 : (4 + 3*(wid-1));
  const int nmt = (wid == 0) ? 4 : 3;

  f32x4 acc[4][7];
  #pragma unroll
  for (int i = 0; i < 4; ++i)
    #pragma unroll
    for (int j = 0; j < 7; ++j) acc[i][j] = (f32x4)0.0f;

  for (int kc = 0; kc < 7; ++kc){
    const int k0 = kc*32;
    // --- stage A (gathered [rel|ent] rows), zero-padded ---
    for (int g = tid; g < 208*8; g += 256){
      int r = g >> 3, gi = g & 7, k = k0 + gi*4;
      uint2 v; v.x = 0u; v.y = 0u;
      if (r < 200 && k < 200){
        int c  = (k < 100) ? c1_s[r] : c2_s[r];
        int kk = (k < 100) ? k : (k - 100);
        size_t idx = (size_t)c*100 + kk;          // always 4-elem aligned
        if (bf) v = *(const uint2*)(emb16 + idx);
        else {
          float4 t = *(const float4*)(emb32 + idx);
          v.x = (u32)f2bu(t.x) | ((u32)f2bu(t.y) << 16);
          v.y = (u32)f2bu(t.z) | ((u32)f2bu(t.w) << 16);
        }
      }
      *(uint2*)(As + r*40 + gi*4) = v;
    }
    // --- stage B (w chunk), zero-padded ---
    for (int g = tid; g < 112*8; g += 256){
      int nn = g >> 3, gi = g & 7, k = k0 + gi*4;
      uint2 v; v.x = 0u; v.y = 0u;
      if (nn < 100 && k < 200){
        size_t idx = (size_t)nn*200 + k;
        if (bf) v = *(const uint2*)(w16 + idx);
        else {
          float4 t = *(const float4*)(w32 + idx);
          v.x = (u32)f2bu(t.x) | ((u32)f2bu(t.y) << 16);
          v.y = (u32)f2bu(t.z) | ((u32)f2bu(t.w) << 16);
        }
      }
      *(uint2*)(Bs + nn*40 + gi*4) = v;
    }
    __syncthreads();

    short8 bfr[7];
    #pragma unroll
    for (int nt = 0; nt < 7; ++nt)
      bfr[nt] = *(const short8*)(Bs + (nt*16 + ln)*40 + quad*8);
    #pragma unroll
    for (int mi = 0; mi < 4; ++mi){
      if (mi < nmt){
        short8 afr = *(const short8*)(As + ((mt0+mi)*16 + ln)*40 + quad*8);
        #pragma unroll
        for (int nt = 0; nt < 7; ++nt)
          acc[mi][nt] = __builtin_amdgcn_mfma_f32_16x16x32_bf16(afr, bfr[nt], acc[mi][nt], 0, 0, 0);
      }
    }
    __syncthreads();
  }

  // --- epilogue: bias + leaky_relu -> out_s (bf16, stride 104) ---
  // C/D layout: col = lane&15, row = quad*4 + reg   [m89-verified]
  #pragma unroll
  for (int mi = 0; mi < 4; ++mi){
    if (mi < nmt){
      int mt = mt0 + mi;
      #pragma unroll
      for (int nt = 0; nt < 7; ++nt){
        int d = nt*16 + ln;
        if (d < 100){
          #pragma unroll
          for (int rg = 0; rg < 4; ++rg){
            int r = mt*16 + quad*4 + rg;
            if (r < 200){
              float x = acc[mi][nt][rg] + bias_s[d];
              x = x > 0.0f ? x : 0.01f*x;
              out_s[r*104 + d] = f2bu(x);
            }
          }
        }
      }
    }
  }
  __syncthreads();

  // --- attention over m (round-2 verified code) ---
  if (tid < 200){
    float acc2 = ldf(attnwb, 0, bf);
    for (int d = 0; d < 100; ++d) acc2 += u2f(out_s[tid*104 + d]) * attnw_s[d];
    logit_s[tid] = acc2;
  }
  __syncthreads();
  red_s[tid] = (tid < 200) ? logit_s[tid] : -3.0e38f;
  __syncthreads();
  for (int off = 128; off > 0; off >>= 1){
    if (tid < off) red_s[tid] = fmaxf(red_s[tid], red_s[tid+off]);
    __syncthreads();
  }
  float mx = red_s[0];
  __syncthreads();
  float ev = 0.0f;
  if (tid < 200){ ev = expf(logit_s[tid] - mx); logit_s[tid] = ev; }
  red_s[tid] = ev;
  __syncthreads();
  for (int off = 128; off > 0; off >>= 1){
    if (tid < off) red_s[tid] += red_s[tid+off];
    __syncthreads();
  }
  float S = red_s[0];
  __syncthreads();

  if (tid < 100){
    float acc2 = 0.0f;
    for (int m = 0; m < 200; ++m) acc2 += u2f(out_s[m*104 + tid]) * logit_s[m];
    oa_s[tid] = acc2 / S;
  }
  __syncthreads();
  if (tid == 0){
    float g = ldf(gatewb, 0, bf) + ldf(gateb, 0, bf);
    for (int d = 0; d < 100; ++d) g += oa_s[d] * gatew_s[d];
    red_s[0] = sigm(g);
  }
  __syncthreads();
  float gate = red_s[0];
  if (tid < 100){
    int c0 = conn[0];
    float self = ldf(emb, (size_t)c0*100 + tid, bf);
    X0[((size_t)f*256 + b)*200 + s*100 + tid] = oa_s[tid]*gate + self*(1.0f - gate);
  }
}

// ---------------------------------------------------------------------------
// Kernel 2: out[r][j] = b1[bEl+j]+b2[bEl+j] + sum_k A[r][k]*W[wEl + j*K + k]
// ---------------------------------------------------------------------------
__global__ __launch_bounds__(256) void k_gemm(
    const float* __restrict__ A, const void* __restrict__ W, size_t wEl,
    const void* __restrict__ b1, const void* __restrict__ b2, size_t bEl,
    const int* __restrict__ flag,
    float* __restrict__ out, int K, int C)
{
  extern __shared__ float a_s[];
  const int bf = *flag;
  const int tid = threadIdx.x;
  const int r = blockIdx.y;
  const float* a = A + (size_t)r*K;
  for (int k = tid; k < K; k += 256) a_s[k] = a[k];
  __syncthreads();
  const int j = blockIdx.x*256 + tid;
  if (j >= C) return;
  float acc = 0.0f;
  if (b1) acc += ldf(b1, bEl + j, bf);
  if (b2) acc += ldf(b2, bEl + j, bf);
  if (bf){
    const u16* w = (const u16*)W + wEl + (size_t)j*K;
    for (int k = 0; k < K; k += 4){
      uint2 wv = *(const uint2*)(w + k);
      acc += a_s[k]   * u2f(wv.x & 0xffffu);
      acc += a_s[k+1] * u2f(wv.x >> 16);
      acc += a_s[k+2] * u2f(wv.y & 0xffffu);
      acc += a_s[k+3] * u2f(wv.y >> 16);
    }
  } else {
    const float* w = (const float*)W + wEl + (size_t)j*K;
    for (int k = 0; k < K; k += 4){
      float4 wv = *(const float4*)(w + k);
      acc += a_s[k]*wv.x + a_s[k+1]*wv.y + a_s[k+2]*wv.z + a_s[k+3]*wv.w;
    }
  }
  out[(size_t)r*C + j] = acc;
}

// ---------------------------------------------------------------------------
// Kernel 3: LSTM recurrent gate GEMM, one timestep, both directions.
// ---------------------------------------------------------------------------
__global__ __launch_bounds__(256) void k_gates(
    const float* __restrict__ G, const float* __restrict__ HC,
    const void* __restrict__ Whh, const int* __restrict__ flag,
    float* __restrict__ GT, int s)
{
  __shared__ float h_s[450];
  const int bf = *flag;
  const int tid = threadIdx.x;
  const int dir = blockIdx.z;
  const int b = blockIdx.y;
  const int t_eff = dir ? (4 - s) : s;
  const float* h = HC + ((size_t)dir*256 + b)*450;
  for (int k = tid; k < 450; k += 256) h_s[k] = h[k];
  __syncthreads();
  const int j = blockIdx.x*256 + tid;
  if (j >= 1800) return;
  float acc = G[(((size_t)dir*5 + t_eff)*256 + b)*1800 + j];
  if (bf){
    const u16* w = (const u16*)Whh + ((size_t)dir*1800 + j)*450;
    for (int k = 0; k < 450; k += 2){
      u32 wv = *(const u32*)(w + k);
      acc += h_s[k]   * u2f(wv & 0xffffu);
      acc += h_s[k+1] * u2f(wv >> 16);
    }
  } else {
    const float* w = (const float*)Whh + ((size_t)dir*1800 + j)*450;
    for (int k = 0; k < 450; k += 2){
      float2 wv = *(const float2*)(w + k);
      acc += h_s[k]*wv.x + h_s[k+1]*wv.y;
    }
  }
  GT[((size_t)dir*256 + b)*1800 + j] = acc;
}

// ---------------------------------------------------------------------------
// Kernel 4: LSTM cell pointwise update.
// ---------------------------------------------------------------------------
__global__ __launch_bounds__(256) void k_cell(
    const float* __restrict__ GT, float* __restrict__ HC,
    float* __restrict__ Y, float* __restrict__ HF, int s, int layer)
{
  int idx = blockIdx.x*256 + threadIdx.x;
  if (idx >= 2*256*450) return;
  int k = idx % 450;
  int rb = idx / 450;
  int b = rb % 256;
  int dir = rb / 256;
  int t_eff = dir ? (4 - s) : s;
  const float* g = GT + ((size_t)dir*256 + b)*1800;
  float gi = g[k], gf = g[450+k], gg = g[900+k], go = g[1350+k];
  float* hp = HC + ((size_t)dir*256 + b)*450 + k;
  float* cp = HC + ((size_t)(2+dir)*256 + b)*450 + k;
  float c = sigm(gf)*(*cp) + sigm(gi)*tanhf(gg);
  float hv = sigm(go)*tanhf(c);
  *cp = c; *hp = hv;
  Y[((size_t)t_eff*256 + b)*900 + dir*450 + k] = hv;
  HF[((size_t)(layer*2+dir)*256 + b)*450 + k] = hv;
}

// ---------------------------------------------------------------------------
// Kernel 5: attention over timesteps + context.
// hidden[b][h][l] = HF_flat[b*1800 + h*2 + l]  (reference reshape quirk)
// ---------------------------------------------------------------------------
__global__ __launch_bounds__(256) void k_attn(
    const float* __restrict__ Y1, const float* __restrict__ HF,
    float* __restrict__ CTX)
{
  __shared__ float red[256];
  __shared__ float sc[10];
  __shared__ float aw[10];
  int b = blockIdx.x, tid = threadIdx.x;
  for (int p = 0; p < 10; ++p){
    int t = p >> 1, l = p & 1;
    float a = 0.0f;
    for (int h = tid; h < 900; h += 256)
      a += Y1[((size_t)t*256 + b)*900 + h] * HF[(size_t)b*1800 + h*2 + l];
    red[tid] = a; __syncthreads();
    for (int off = 128; off > 0; off >>= 1){
      if (tid < off) red[tid] += red[tid+off];
      __syncthreads();
    }
    if (tid == 0) sc[p] = red[0];
    __syncthreads();
  }
  if (tid < 2){
    int l = tid;
    float mxv = -3.0e38f;
    for (int t = 0; t < 5; ++t) mxv = fmaxf(mxv, sc[t*2+l]);
    float e[5], sum = 0.0f;
    for (int t = 0; t < 5; ++t){ e[t] = expf(sc[t*2+l]-mxv); sum += e[t]; }
    for (int t = 0; t < 5; ++t) aw[t*2+l] = e[t]/sum;
  }
  __syncthreads();
  for (int h = tid; h < 900; h += 256){
    float v0 = 0.0f, v1 = 0.0f;
    for (int t = 0; t < 5; ++t){
      float y = Y1[((size_t)t*256 + b)*900 + h];
      v0 += y*aw[t*2+0]; v1 += y*aw[t*2+1];
    }
    CTX[(size_t)b*1800 + h*2 + 0] = v0;
    CTX[(size_t)b*1800 + h*2 + 1] = v1;
  }
}

__device__ __forceinline__ float bred128(float v, float* red, int tid){
  red[tid] = v; __syncthreads();
  for (int off = 64; off > 0; off >>= 1){
    if (tid < off) red[tid] += red[tid+off];
    __syncthreads();
  }
  float r = red[0]; __syncthreads();
  return r;
}

// ---------------------------------------------------------------------------
// Kernel 6: analytic meta-gradient -> rel_q, norm_q. One block per b.
// ---------------------------------------------------------------------------
__global__ __launch_bounds__(128) void k_grad(
    const void* __restrict__ sup, const void* __restrict__ supn,
    const void* __restrict__ normv, const float* __restrict__ REL,
    const int* __restrict__ flag,
    float* __restrict__ RELQ, float* __restrict__ NORMQ)
{
  __shared__ float red[128];
  __shared__ float nv[100], rl[100], acc[100];
  const int bf = *flag;
  int b = blockIdx.x, tid = threadIdx.x;
  if (tid < 100){
    nv[tid] = ldf(normv, b*100+tid, bf);
    rl[tid] = REL[b*100+tid];
    acc[tid] = 0.0f;
  }
  __syncthreads();
  float nvd = (tid < 100) ? nv[tid] : 0.0f;
  float rld = (tid < 100) ? rl[tid] : 0.0f;
  for (int j = 0; j < 5; ++j){
    float h1=0.f,t1=0.f,h2=0.f,t2=0.f;
    if (tid < 100){
      size_t base = (size_t)(b*5+j)*200;
      h1 = ldf(sup,  base + tid, bf);  t1 = ldf(sup,  base + 100 + tid, bf);
      h2 = ldf(supn, base + tid, bf);  t2 = ldf(supn, base + 100 + tid, bf);
    }
    float hd1 = bred128(h1*nvd, red, tid);
    float td1 = bred128(t1*nvd, red, tid);
    float hd2 = bred128(h2*nvd, red, tid);
    float td2 = bred128(t2*nvd, red, tid);
    float upd = (h1 - hd1*nvd) + rld - (t1 - td1*nvd);
    float und = (h2 - hd2*nvd) + rld - (t2 - td2*nvd);
    if (tid >= 100){ upd = 0.0f; und = 0.0f; }
    float np2 = bred128(upd*upd, red, tid);
    float nn2 = bred128(und*und, red, tid);
    float p = -sqrtf(np2), nsc = -sqrtf(nn2);
    if ((1.0f - (p - nsc) > 0.0f) && tid < 100)
      acc[tid] += upd/sqrtf(np2) - und/sqrtf(nn2);
  }
  __syncthreads();
  if (tid < 100){
    float g = acc[tid] * (1.0f/1280.0f);
    RELQ[b*100+tid]  = rl[tid] - 5.0f*g;
    NORMQ[b*100+tid] = nv[tid] - 5.0f*g;
  }
}

// ---------------------------------------------------------------------------
// Kernel 7: final scores (10 query + 512 negative per b). Output per flag.
// ---------------------------------------------------------------------------
__global__ __launch_bounds__(192) void k_score(
    const void* __restrict__ query, const void* __restrict__ neg,
    const float* __restrict__ RELQ, const float* __restrict__ NORMQ,
    const int* __restrict__ flag, void* __restrict__ out)
{
  __shared__ float nq[100], rq[100];
  const int bf = *flag;
  int b = blockIdx.x, tid = threadIdx.x;
  if (tid < 100){ nq[tid] = NORMQ[b*100+tid]; rq[tid] = RELQ[b*100+tid]; }
  __syncthreads();
  int qi = blockIdx.y*192 + tid;
  if (qi >= 522) return;
  const void* src = (qi < 10) ? query : neg;
  size_t row = (qi < 10) ? ((size_t)b*10 + qi) : ((size_t)b*512 + qi - 10);
  size_t base = row*200;
  float hd = 0.0f, td = 0.0f;
  for (int d = 0; d < 100; ++d){
    hd += ldf(src, base + d, bf)       * nq[d];
    td += ldf(src, base + 100 + d, bf) * nq[d];
  }
  float s2 = 0.0f;
  for (int d = 0; d < 100; ++d){
    float u = (ldf(src, base + d, bf) - hd*nq[d]) + rq[d]
            - (ldf(src, base + 100 + d, bf) - td*nq[d]);
    s2 += u*u;
  }
  float sc = -sqrtf(s2);
  size_t oi = (qi < 10) ? ((size_t)b*10 + qi) : (2560 + (size_t)b*512 + (qi - 10));
  if (bf) ((u16*)out)[oi] = f2bu(sc);
  else    ((float*)out)[oi] = sc;
}

// ---------------------------------------------------------------------------
extern "C" void kernel_launch(void* const* d_in, const int* in_sizes, int n_in,
                              void* d_out, int out_size, void* d_ws, size_t ws_size,
                              hipStream_t stream)
{
  const void* support = d_in[0];
  const void* supneg  = d_in[1];
  const void* query   = d_in[2];
  const void* negat   = d_in[3];
  const void* normv   = d_in[4];
  const int* left     = (const int*)d_in[5];
  const int* right    = (const int*)d_in[6];
  const void* emb     = d_in[7];
  const void* gcnw    = d_in[8];
  const void* gcnwb   = d_in[9];
  const void* gcnb    = d_in[10];
  const void* attnw   = d_in[11];
  const void* attnwb  = d_in[12];
  const void* gatew   = d_in[13];
  const void* gatewb  = d_in[14];
  const void* gateb   = d_in[15];
  const void* Wih0    = d_in[16];
  const void* Whh0    = d_in[17];
  const void* bih0    = d_in[18];
  const void* bhh0    = d_in[19];
  const void* Wih1    = d_in[20];
  const void* Whh1    = d_in[21];
  const void* bih1    = d_in[22];
  const void* bhh1    = d_in[23];
  const void* outw    = d_in[24];
  const void* outb    = d_in[25];

  int*   dflag = (int*)d_ws;
  float* ws    = (float*)d_ws + 16;
  float* X0   = ws;                  // 5*256*200      = 256000
  float* G    = X0 + 256000;         // 2*5*256*1800   = 4608000
  float* Y0   = G + 4608000;         // 5*256*900      = 1152000
  float* Y1   = Y0 + 1152000;        // 1152000
  float* HF   = Y1 + 1152000;        // 4*256*450      = 460800
  float* HC   = HF + 460800;         // h,c (2 dirs)   = 460800
  float* CTX  = HC + 460800;         // 256*1800       = 460800
  float* RELb = CTX + 460800;        // 25600
  float* RELQ = RELb + 25600;
  float* NORMQ= RELQ + 25600;
  float* GT   = NORMQ + 25600;       // 2*256*1800     = 921600

  k_detect<<<1, 64, 0, stream>>>((const u32*)normv, dflag);

  k_gcn<<<2560, 256, 0, stream>>>(left, right, emb, gcnw, gcnwb, gcnb,
                                  attnw, attnwb, gatew, gatewb, gateb,
                                  dflag, X0);
  hipMemsetAsync(HC, 0, 460800*sizeof(float), stream);
  k_gemm<<<dim3(8,1280), 256, 200*4, stream>>>(X0, Wih0, 0,      bih0, bhh0, 0,
                                               dflag, G,           200, 1800);
  k_gemm<<<dim3(8,1280), 256, 200*4, stream>>>(X0, Wih0, 360000, bih0, bhh0, 1800,
                                               dflag, G + 2304000, 200, 1800);
  for (int s = 0; s < 5; ++s){
    k_gates<<<dim3(8,256,2), 256, 0, stream>>>(G, HC, Whh0, dflag, GT, s);
    k_cell<<<900, 256, 0, stream>>>(GT, HC, Y0, HF, s, 0);
  }
  hipMemsetAsync(HC, 0, 460800*sizeof(float), stream);
  k_gemm<<<dim3(8,1280), 256, 900*4, stream>>>(Y0, Wih1, 0,       bih1, bhh1, 0,
                                               dflag, G,           900, 1800);
  k_gemm<<<dim3(8,1280), 256, 900*4, stream>>>(Y0, Wih1, 1620000, bih1, bhh1, 1800,
                                               dflag, G + 2304000, 900, 1800);
  for (int s = 0; s < 5; ++s){
    k_gates<<<dim3(8,256,2), 256, 0, stream>>>(G, HC, Whh1, dflag, GT, s);
    k_cell<<<900, 256, 0, stream>>>(GT, HC, Y1, HF, s, 1);
  }
  k_attn<<<256, 256, 0, stream>>>(Y1, HF, CTX);
  k_gemm<<<dim3(1,256), 256, 1800*4, stream>>>(CTX, outw, 0, outb, nullptr, 0,
                                               dflag, RELb, 1800, 100);
  k_grad<<<256, 128, 0, stream>>>(support, supneg, normv, RELb, dflag, RELQ, NORMQ);
  k_score<<<dim3(256,3), 192, 0, stream>>>(query, negat, RELQ, NORMQ, dflag, d_out);
}

// Round 4
// 1275.235 us; speedup vs baseline: 5.2587x; 3.4350x over previous
//
#include <hip/hip_runtime.h>

typedef unsigned short u16;
typedef unsigned int   u32;
typedef __attribute__((ext_vector_type(8))) short short8;
typedef __attribute__((ext_vector_type(4))) float f32x4;

__device__ __forceinline__ float u2f(u32 u){
  union { u32 i; float f; } v; v.i = u << 16; return v.f;
}
__device__ __forceinline__ u16 f2bu(float f){
  union { float f; u32 i; } v; v.f = f;
  u32 i = v.i;
  i += 0x7fffu + ((i >> 16) & 1u);   // round-to-nearest-even
  return (u16)(i >> 16);
}
__device__ __forceinline__ float sigm(float x){ return 1.0f/(1.0f + expf(-x)); }
__device__ __forceinline__ float ldf(const void* p, size_t i, int bf){
  return bf ? u2f(((const u16*)p)[i]) : ((const float*)p)[i];
}

// ---------------------------------------------------------------------------
// Kernel 0: dtype detector (bf16 vs f32 device buffers).
// ---------------------------------------------------------------------------
__global__ __launch_bounds__(64) void k_detect(const u32* __restrict__ nv,
                                               int* __restrict__ flag)
{
  int i = threadIdx.x;
  u32 w = nv[i];
  u32 e = (w >> 7) & 0xffu;
  bool sane = (e >= 100u && e <= 140u);
  unsigned long long m = __ballot(sane);
  if (i == 0) *flag = (__popcll(m) >= 40) ? 1 : 0;
}

// ---------------------------------------------------------------------------
// Kernel P: pack weights -> bf16, rows x Kp, zero-padded k>=K.
// ---------------------------------------------------------------------------
__global__ __launch_bounds__(256) void k_pack(
    const void* __restrict__ src, u16* __restrict__ dst,
    int K, int Kp, int total, const int* __restrict__ flag)
{
  const int bf = *flag;
  int idx = blockIdx.x*256 + threadIdx.x;
  if (idx >= total) return;
  int r = idx / Kp, k = idx - r*Kp;
  u16 v = 0;
  if (k < K){
    size_t si = (size_t)r*K + k;
    v = bf ? ((const u16*)src)[si] : f2bu(((const float*)src)[si]);
  }
  dst[idx] = v;
}

// ---------------------------------------------------------------------------
// Kernel 1: neighbor encoder, MFMA (round-3 verified). Writes X0bf (bf16,
// row stride 224, zero-padded by host memset).
// ---------------------------------------------------------------------------
__global__ __launch_bounds__(256) void k_gcn(
    const int* __restrict__ left, const int* __restrict__ right,
    const void* __restrict__ emb,
    const void* __restrict__ gcnw, const void* __restrict__ gcnwb, const void* __restrict__ gcnb,
    const void* __restrict__ attnw, const void* __restrict__ attnwb,
    const void* __restrict__ gatew, const void* __restrict__ gatewb, const void* __restrict__ gateb,
    const int* __restrict__ flag,
    u16* __restrict__ X0bf)
{
  __shared__ __align__(16) char smem[41600];
  __shared__ int c1_s[200], c2_s[200];
  __shared__ float logit_s[256], red_s[256];
  __shared__ float attnw_s[100], gatew_s[100], bias_s[100], oa_s[100];

  u16* As    = (u16*)smem;              // [208][40]
  u16* Bs    = (u16*)(smem + 16640);    // [112][40]
  u16* out_s = (u16*)smem;              // [200][104] after K-loop

  const int bf  = *flag;
  const int tid = threadIdx.x;
  const int n   = blockIdx.x;
  const int b   = n & 255;
  const int fs  = n >> 8;
  const int s   = fs & 1;
  const int f   = fs >> 1;
  const int* conn = (s == 0 ? left : right) + (size_t)(f*256 + b)*600;

  const u16*   emb16 = (const u16*)emb;
  const float* emb32 = (const float*)emb;
  const u16*   w16   = (const u16*)gcnw;
  const float* w32   = (const float*)gcnw;

  if (tid < 200){ c1_s[tid] = conn[tid*3+1]; c2_s[tid] = conn[tid*3+2]; }
  if (tid < 100){
    attnw_s[tid] = ldf(attnw, tid, bf);
    gatew_s[tid] = ldf(gatew, tid, bf);
    bias_s[tid]  = ldf(gcnwb, tid, bf) + ldf(gcnb, tid, bf);
  }
  __syncthreads();

  const int wid  = tid >> 6, lane = tid & 63, ln = lane & 15, quad = lane >> 4;
  const int mt0 = (wid == 0) ? 0 : (4 + 3*(wid-1));
  const int nmt = (wid == 0) ? 4 : 3;

  f32x4 acc[4][7];
  #pragma unroll
  for (int i = 0; i < 4; ++i)
    #pragma unroll
    for (int j = 0; j < 7; ++j) acc[i][j] = (f32x4)0.0f;

  for (int kc = 0; kc < 7; ++kc){
    const int k0 = kc*32;
    for (int g = tid; g < 208*8; g += 256){
      int r = g >> 3, gi = g & 7, k = k0 + gi*4;
      uint2 v; v.x = 0u; v.y = 0u;
      if (r < 200 && k < 200){
        int c  = (k < 100) ? c1_s[r] : c2_s[r];
        int kk = (k < 100) ? k : (k - 100);
        size_t idx = (size_t)c*100 + kk;
        if (bf) v = *(const uint2*)(emb16 + idx);
        else {
          float4 t = *(const float4*)(emb32 + idx);
          v.x = (u32)f2bu(t.x) | ((u32)f2bu(t.y) << 16);
          v.y = (u32)f2bu(t.z) | ((u32)f2bu(t.w) << 16);
        }
      }
      *(uint2*)(As + r*40 + gi*4) = v;
    }
    for (int g = tid; g < 112*8; g += 256){
      int nn = g >> 3, gi = g & 7, k = k0 + gi*4;
      uint2 v; v.x = 0u; v.y = 0u;
      if (nn < 100 && k < 200){
        size_t idx = (size_t)nn*200 + k;
        if (bf) v = *(const uint2*)(w16 + idx);
        else {
          float4 t = *(const float4*)(w32 + idx);
          v.x = (u32)f2bu(t.x) | ((u32)f2bu(t.y) << 16);
          v.y = (u32)f2bu(t.z) | ((u32)f2bu(t.w) << 16);
        }
      }
      *(uint2*)(Bs + nn*40 + gi*4) = v;
    }
    __syncthreads();

    short8 bfr[7];
    #pragma unroll
    for (int nt = 0; nt < 7; ++nt)
      bfr[nt] = *(const short8*)(Bs + (nt*16 + ln)*40 + quad*8);
    #pragma unroll
    for (int mi = 0; mi < 4; ++mi){
      if (mi < nmt){
        short8 afr = *(const short8*)(As + ((mt0+mi)*16 + ln)*40 + quad*8);
        #pragma unroll
        for (int nt = 0; nt < 7; ++nt)
          acc[mi][nt] = __builtin_amdgcn_mfma_f32_16x16x32_bf16(afr, bfr[nt], acc[mi][nt], 0, 0, 0);
      }
    }
    __syncthreads();
  }

  #pragma unroll
  for (int mi = 0; mi < 4; ++mi){
    if (mi < nmt){
      int mt = mt0 + mi;
      #pragma unroll
      for (int nt = 0; nt < 7; ++nt){
        int d = nt*16 + ln;
        if (d < 100){
          #pragma unroll
          for (int rg = 0; rg < 4; ++rg){
            int r = mt*16 + quad*4 + rg;
            if (r < 200){
              float x = acc[mi][nt][rg] + bias_s[d];
              x = x > 0.0f ? x : 0.01f*x;
              out_s[r*104 + d] = f2bu(x);
            }
          }
        }
      }
    }
  }
  __syncthreads();

  if (tid < 200){
    float acc2 = ldf(attnwb, 0, bf);
    for (int d = 0; d < 100; ++d) acc2 += u2f(out_s[tid*104 + d]) * attnw_s[d];
    logit_s[tid] = acc2;
  }
  __syncthreads();
  red_s[tid] = (tid < 200) ? logit_s[tid] : -3.0e38f;
  __syncthreads();
  for (int off = 128; off > 0; off >>= 1){
    if (tid < off) red_s[tid] = fmaxf(red_s[tid], red_s[tid+off]);
    __syncthreads();
  }
  float mx = red_s[0];
  __syncthreads();
  float ev = 0.0f;
  if (tid < 200){ ev = expf(logit_s[tid] - mx); logit_s[tid] = ev; }
  red_s[tid] = ev;
  __syncthreads();
  for (int off = 128; off > 0; off >>= 1){
    if (tid < off) red_s[tid] += red_s[tid+off];
    __syncthreads();
  }
  float S = red_s[0];
  __syncthreads();

  if (tid < 100){
    float acc2 = 0.0f;
    for (int m = 0; m < 200; ++m) acc2 += u2f(out_s[m*104 + tid]) * logit_s[m];
    oa_s[tid] = acc2 / S;
  }
  __syncthreads();
  if (tid == 0){
    float g = ldf(gatewb, 0, bf) + ldf(gateb, 0, bf);
    for (int d = 0; d < 100; ++d) g += oa_s[d] * gatew_s[d];
    red_s[0] = sigm(g);
  }
  __syncthreads();
  float gate = red_s[0];
  if (tid < 100){
    int c0 = conn[0];
    float self = ldf(emb, (size_t)c0*100 + tid, bf);
    X0bf[((size_t)f*256 + b)*224 + s*100 + tid] = f2bu(oa_s[tid]*gate + self*(1.0f - gate));
  }
}

// ---------------------------------------------------------------------------
// Kernel M: MFMA GEMM. out[z][row][col] = sum_k A[z][row][k]*B[z][col][k]
//           (+ bias1/bias2[z*biasStride+col]) (+ addend_z[row*N+col], bf16).
// A,B bf16, lda/ldb multiples of 32, zero-padded. M multiple of 128.
// Block 256 thr = 4 waves (2x2), each wave 64x64 via 4x4 MFMA 16x16x32.
// ---------------------------------------------------------------------------
__global__ __launch_bounds__(256) void k_mgemm(
    const u16* __restrict__ A, int lda, size_t Astride,
    const u16* __restrict__ B, int ldb, size_t Bstride,
    const void* __restrict__ b1, const void* __restrict__ b2, int biasStride,
    const int* __restrict__ flag,
    const u16* __restrict__ add0, const u16* __restrict__ add1,
    void* __restrict__ out, int outBf, size_t Ostride,
    int N, int KC)
{
  __shared__ __align__(16) u16 As[128*40];
  __shared__ __align__(16) u16 Bs[128*40];
  const int tid = threadIdx.x;
  const int z  = blockIdx.z;
  const int nb = blockIdx.x, mb = blockIdx.y;
  const u16* Az = A + (size_t)z*Astride;
  const u16* Bz = B + (size_t)z*Bstride;
  const int bf = *flag;

  const int wid = tid >> 6, lane = tid & 63, ln = lane & 15, quad = lane >> 4;
  const int wm = wid >> 1, wn = wid & 1;

  f32x4 acc[4][4];
  #pragma unroll
  for (int i = 0; i < 4; ++i)
    #pragma unroll
    for (int j = 0; j < 4; ++j) acc[i][j] = (f32x4)0.0f;

  const int srow = tid >> 1;
  const int koff = (tid & 1)*16;
  const int rowA = mb*128 + srow;
  const int rowB = nb*128 + srow;
  const bool bok = (rowB < N);

  for (int kc = 0; kc < KC; ++kc){
    const int k0 = kc*32 + koff;
    short8 av = *(const short8*)(Az + (size_t)rowA*lda + k0);
    short8 bv = (short8)0;
    if (bok) bv = *(const short8*)(Bz + (size_t)rowB*ldb + k0);
    *(short8*)(As + srow*40 + koff) = av;
    *(short8*)(Bs + srow*40 + koff) = bv;
    __syncthreads();
    short8 af[4], bfr[4];
    #pragma unroll
    for (int i = 0; i < 4; ++i)
      af[i] = *(const short8*)(As + (wm*64 + i*16 + ln)*40 + quad*8);
    #pragma unroll
    for (int j = 0; j < 4; ++j)
      bfr[j] = *(const short8*)(Bs + (wn*64 + j*16 + ln)*40 + quad*8);
    #pragma unroll
    for (int i = 0; i < 4; ++i)
      #pragma unroll
      for (int j = 0; j < 4; ++j)
        acc[i][j] = __builtin_amdgcn_mfma_f32_16x16x32_bf16(af[i], bfr[j], acc[i][j], 0, 0, 0);
    __syncthreads();
  }

  const u16* addz = (z == 0) ? add0 : add1;
  #pragma unroll
  for (int j = 0; j < 4; ++j){
    int col = nb*128 + wn*64 + j*16 + ln;
    if (col < N){
      float bias = 0.0f;
      if (b1) bias += ldf(b1, (size_t)z*biasStride + col, bf);
      if (b2) bias += ldf(b2, (size_t)z*biasStride + col, bf);
      #pragma unroll
      for (int i = 0; i < 4; ++i){
        #pragma unroll
        for (int rg = 0; rg < 4; ++rg){
          int row = mb*128 + wm*64 + i*16 + quad*4 + rg;
          float v = acc[i][j][rg] + bias;
          if (addz) v += u2f(addz[(size_t)row*N + col]);
          size_t oi = (size_t)z*Ostride + (size_t)row*N + col;
          if (outBf) ((u16*)out)[oi] = f2bu(v);
          else       ((float*)out)[oi] = v;
        }
      }
    }
  }
}

// ---------------------------------------------------------------------------
// Kernel 4: LSTM cell pointwise update. Writes h -> Hbf (bf16, stride 480),
// y -> Y0bf (bf16, stride 928) or Y1 (f32, stride 900), finals -> HF.
// ---------------------------------------------------------------------------
__global__ __launch_bounds__(256) void k_cell(
    const float* __restrict__ GT, float* __restrict__ HC,
    u16* __restrict__ Hbf, u16* __restrict__ Ybf, float* __restrict__ Yf,
    float* __restrict__ HF, int s, int layer)
{
  int idx = blockIdx.x*256 + threadIdx.x;
  if (idx >= 2*256*450) return;
  int k = idx % 450;
  int rb = idx / 450;
  int b = rb % 256;
  int dir = rb / 256;
  int t_eff = dir ? (4 - s) : s;
  const float* g = GT + ((size_t)dir*256 + b)*1800;
  float gi = g[k], gf = g[450+k], gg = g[900+k], go = g[1350+k];
  float* cp = HC + ((size_t)(2+dir)*256 + b)*450 + k;
  float c = sigm(gf)*(*cp) + sigm(gi)*tanhf(gg);
  float hv = sigm(go)*tanhf(c);
  *cp = c;
  Hbf[((size_t)dir*256 + b)*480 + k] = f2bu(hv);
  if (Ybf) Ybf[((size_t)t_eff*256 + b)*928 + dir*450 + k] = f2bu(hv);
  else     Yf [((size_t)t_eff*256 + b)*900 + dir*450 + k] = hv;
  HF[((size_t)(layer*2+dir)*256 + b)*450 + k] = hv;
}

// ---------------------------------------------------------------------------
// Kernel 5: attention over timesteps + context.
// hidden[b][h][l] = HF_flat[b*1800 + h*2 + l]  (reference reshape quirk)
// ---------------------------------------------------------------------------
__global__ __launch_bounds__(256) void k_attn(
    const float* __restrict__ Y1, const float* __restrict__ HF,
    float* __restrict__ CTX)
{
  __shared__ float red[256];
  __shared__ float sc[10];
  __shared__ float aw[10];
  int b = blockIdx.x, tid = threadIdx.x;
  for (int p = 0; p < 10; ++p){
    int t = p >> 1, l = p & 1;
    float a = 0.0f;
    for (int h = tid; h < 900; h += 256)
      a += Y1[((size_t)t*256 + b)*900 + h] * HF[(size_t)b*1800 + h*2 + l];
    red[tid] = a; __syncthreads();
    for (int off = 128; off > 0; off >>= 1){
      if (tid < off) red[tid] += red[tid+off];
      __syncthreads();
    }
    if (tid == 0) sc[p] = red[0];
    __syncthreads();
  }
  if (tid < 2){
    int l = tid;
    float mxv = -3.0e38f;
    for (int t = 0; t < 5; ++t) mxv = fmaxf(mxv, sc[t*2+l]);
    float e[5], sum = 0.0f;
    for (int t = 0; t < 5; ++t){ e[t] = expf(sc[t*2+l]-mxv); sum += e[t]; }
    for (int t = 0; t < 5; ++t) aw[t*2+l] = e[t]/sum;
  }
  __syncthreads();
  for (int h = tid; h < 900; h += 256){
    float v0 = 0.0f, v1 = 0.0f;
    for (int t = 0; t < 5; ++t){
      float y = Y1[((size_t)t*256 + b)*900 + h];
      v0 += y*aw[t*2+0]; v1 += y*aw[t*2+1];
    }
    CTX[(size_t)b*1800 + h*2 + 0] = v0;
    CTX[(size_t)b*1800 + h*2 + 1] = v1;
  }
}

// ---------------------------------------------------------------------------
// Kernel 2s: scalar GEMM (kept only for CTX @ out_w, C=100).
// ---------------------------------------------------------------------------
__global__ __launch_bounds__(256) void k_gemm(
    const float* __restrict__ A, const void* __restrict__ W, size_t wEl,
    const void* __restrict__ b1, const void* __restrict__ b2, size_t bEl,
    const int* __restrict__ flag,
    float* __restrict__ out, int K, int C)
{
  extern __shared__ float a_s[];
  const int bf = *flag;
  const int tid = threadIdx.x;
  const int r = blockIdx.y;
  const float* a = A + (size_t)r*K;
  for (int k = tid; k < K; k += 256) a_s[k] = a[k];
  __syncthreads();
  const int j = blockIdx.x*256 + tid;
  if (j >= C) return;
  float acc = 0.0f;
  if (b1) acc += ldf(b1, bEl + j, bf);
  if (b2) acc += ldf(b2, bEl + j, bf);
  if (bf){
    const u16* w = (const u16*)W + wEl + (size_t)j*K;
    for (int k = 0; k < K; k += 4){
      uint2 wv = *(const uint2*)(w + k);
      acc += a_s[k]   * u2f(wv.x & 0xffffu);
      acc += a_s[k+1] * u2f(wv.x >> 16);
      acc += a_s[k+2] * u2f(wv.y & 0xffffu);
      acc += a_s[k+3] * u2f(wv.y >> 16);
    }
  } else {
    const float* w = (const float*)W + wEl + (size_t)j*K;
    for (int k = 0; k < K; k += 4){
      float4 wv = *(const float4*)(w + k);
      acc += a_s[k]*wv.x + a_s[k+1]*wv.y + a_s[k+2]*wv.z + a_s[k+3]*wv.w;
    }
  }
  out[(size_t)r*C + j] = acc;
}

__device__ __forceinline__ float bred128(float v, float* red, int tid){
  red[tid] = v; __syncthreads();
  for (int off = 64; off > 0; off >>= 1){
    if (tid < off) red[tid] += red[tid+off];
    __syncthreads();
  }
  float r = red[0]; __syncthreads();
  return r;
}

// ---------------------------------------------------------------------------
// Kernel 6: analytic meta-gradient -> rel_q, norm_q. One block per b.
// ---------------------------------------------------------------------------
__global__ __launch_bounds__(128) void k_grad(
    const void* __restrict__ sup, const void* __restrict__ supn,
    const void* __restrict__ normv, const float* __restrict__ REL,
    const int* __restrict__ flag,
    float* __restrict__ RELQ, float* __restrict__ NORMQ)
{
  __shared__ float red[128];
  __shared__ float nv[100], rl[100], acc[100];
  const int bf = *flag;
  int b = blockIdx.x, tid = threadIdx.x;
  if (tid < 100){
    nv[tid] = ldf(normv, b*100+tid, bf);
    rl[tid] = REL[b*100+tid];
    acc[tid] = 0.0f;
  }
  __syncthreads();
  float nvd = (tid < 100) ? nv[tid] : 0.0f;
  float rld = (tid < 100) ? rl[tid] : 0.0f;
  for (int j = 0; j < 5; ++j){
    float h1=0.f,t1=0.f,h2=0.f,t2=0.f;
    if (tid < 100){
      size_t base = (size_t)(b*5+j)*200;
      h1 = ldf(sup,  base + tid, bf);  t1 = ldf(sup,  base + 100 + tid, bf);
      h2 = ldf(supn, base + tid, bf);  t2 = ldf(supn, base + 100 + tid, bf);
    }
    float hd1 = bred128(h1*nvd, red, tid);
    float td1 = bred128(t1*nvd, red, tid);
    float hd2 = bred128(h2*nvd, red, tid);
    float td2 = bred128(t2*nvd, red, tid);
    float upd = (h1 - hd1*nvd) + rld - (t1 - td1*nvd);
    float und = (h2 - hd2*nvd) + rld - (t2 - td2*nvd);
    if (tid >= 100){ upd = 0.0f; und = 0.0f; }
    float np2 = bred128(upd*upd, red, tid);
    float nn2 = bred128(und*und, red, tid);
    float p = -sqrtf(np2), nsc = -sqrtf(nn2);
    if ((1.0f - (p - nsc) > 0.0f) && tid < 100)
      acc[tid] += upd/sqrtf(np2) - und/sqrtf(nn2);
  }
  __syncthreads();
  if (tid < 100){
    float g = acc[tid] * (1.0f/1280.0f);
    RELQ[b*100+tid]  = rl[tid] - 5.0f*g;
    NORMQ[b*100+tid] = nv[tid] - 5.0f*g;
  }
}

// ---------------------------------------------------------------------------
// Kernel 7: final scores (10 query + 512 negative per b). Output per flag.
// ---------------------------------------------------------------------------
__global__ __launch_bounds__(192) void k_score(
    const void* __restrict__ query, const void* __restrict__ neg,
    const float* __restrict__ RELQ, const float* __restrict__ NORMQ,
    const int* __restrict__ flag, void* __restrict__ out)
{
  __shared__ float nq[100], rq[100];
  const int bf = *flag;
  int b = blockIdx.x, tid = threadIdx.x;
  if (tid < 100){ nq[tid] = NORMQ[b*100+tid]; rq[tid] = RELQ[b*100+tid]; }
  __syncthreads();
  int qi = blockIdx.y*192 + tid;
  if (qi >= 522) return;
  const void* src = (qi < 10) ? query : neg;
  size_t row = (qi < 10) ? ((size_t)b*10 + qi) : ((size_t)b*512 + qi - 10);
  size_t base = row*200;
  float hd = 0.0f, td = 0.0f;
  for (int d = 0; d < 100; ++d){
    hd += ldf(src, base + d, bf)       * nq[d];
    td += ldf(src, base + 100 + d, bf) * nq[d];
  }
  float s2 = 0.0f;
  for (int d = 0; d < 100; ++d){
    float u = (ldf(src, base + d, bf) - hd*nq[d]) + rq[d]
            - (ldf(src, base + 100 + d, bf) - td*nq[d]);
    s2 += u*u;
  }
  float sc = -sqrtf(s2);
  size_t oi = (qi < 10) ? ((size_t)b*10 + qi) : (2560 + (size_t)b*512 + (qi - 10));
  if (bf) ((u16*)out)[oi] = f2bu(sc);
  else    ((float*)out)[oi] = sc;
}

// ---------------------------------------------------------------------------
extern "C" void kernel_launch(void* const* d_in, const int* in_sizes, int n_in,
                              void* d_out, int out_size, void* d_ws, size_t ws_size,
                              hipStream_t stream)
{
  const void* support = d_in[0];
  const void* supneg  = d_in[1];
  const void* query   = d_in[2];
  const void* negat   = d_in[3];
  const void* normv   = d_in[4];
  const int* left     = (const int*)d_in[5];
  const int* right    = (const int*)d_in[6];
  const void* emb     = d_in[7];
  const void* gcnw    = d_in[8];
  const void* gcnwb   = d_in[9];
  const void* gcnb    = d_in[10];
  const void* attnw   = d_in[11];
  const void* attnwb  = d_in[12];
  const void* gatew   = d_in[13];
  const void* gatewb  = d_in[14];
  const void* gateb   = d_in[15];
  const void* Wih0    = d_in[16];
  const void* Whh0    = d_in[17];
  const void* bih0    = d_in[18];
  const void* bhh0    = d_in[19];
  const void* Wih1    = d_in[20];
  const void* Whh1    = d_in[21];
  const void* bih1    = d_in[22];
  const void* bhh1    = d_in[23];
  const void* outw    = d_in[24];
  const void* outb    = d_in[25];

  int*   dflag = (int*)d_ws;
  float* fws   = (float*)d_ws + 16;
  // f32 region
  float* Y1   = fws;                 // 5*256*900  = 1,152,000
  float* HF   = Y1 + 1152000;        // 4*256*450  =   460,800
  float* HC   = HF + 460800;         //               460,800 (c-state in [2..4))
  float* CTX  = HC + 460800;         //               460,800
  float* RELb = CTX + 460800;        //    25,600
  float* RELQ = RELb + 25600;        //    25,600
  float* NORMQ= RELQ + 25600;        //    25,600
  float* GT   = NORMQ + 25600;       // 2*256*1800 =   921,600
  float* fend = GT + 921600;
  // u16 region (16B-aligned: fend offset is a multiple of 16 floats)
  u16* Gb   = (u16*)fend;            // 2*5*256*1800 = 4,608,000
  u16* X0bf = Gb + 4608000;          // 1280*224     =   286,720
  u16* Y0bf = X0bf + 286720;         // 1280*928     = 1,187,840
  u16* Hbf  = Y0bf + 1187840;        // 2*256*480    =   245,760
  u16* Wp   = Hbf + 245760;          // 3600*928 max = 3,340,800
  u16* Whp  = Wp + 3340800;          // 3600*480     = 1,728,000
  // total ≈ 36.9 MB

  k_detect<<<1, 64, 0, stream>>>((const u32*)normv, dflag);

  // neighbor encoder -> X0bf (memset for zero pad first)
  hipMemsetAsync(X0bf, 0, 286720*sizeof(u16), stream);
  k_gcn<<<2560, 256, 0, stream>>>(left, right, emb, gcnw, gcnwb, gcnb,
                                  attnw, attnwb, gatew, gatewb, gateb,
                                  dflag, X0bf);

  // ---- layer 0 ----
  hipMemsetAsync(Y0bf, 0, 1187840*sizeof(u16), stream);
  hipMemsetAsync(Hbf, 0, 245760*sizeof(u16), stream);
  hipMemsetAsync(HC, 0, 460800*sizeof(float), stream);
  k_pack<<<(3600*224+255)/256, 256, 0, stream>>>(Wih0, Wp,  200, 224, 3600*224, dflag);
  k_pack<<<(3600*480+255)/256, 256, 0, stream>>>(Whh0, Whp, 450, 480, 3600*480, dflag);
  // input projection: G[z][t][b][:] (bf16 out)
  k_mgemm<<<dim3(15,10,2), 256, 0, stream>>>(
      X0bf, 224, 0, Wp, 224, (size_t)1800*224,
      bih0, bhh0, 1800, dflag, nullptr, nullptr,
      Gb, 1, 2304000, 1800, 7);
  for (int s = 0; s < 5; ++s){
    k_mgemm<<<dim3(15,2,2), 256, 0, stream>>>(
        Hbf, 480, (size_t)256*480, Whp, 480, (size_t)1800*480,
        nullptr, nullptr, 0, dflag,
        Gb + (size_t)s*460800, Gb + (size_t)(9-s)*460800,
        GT, 0, 460800, 1800, 15);
    k_cell<<<900, 256, 0, stream>>>(GT, HC, Hbf, Y0bf, nullptr, HF, s, 0);
  }

  // ---- layer 1 ----
  hipMemsetAsync(Hbf, 0, 245760*sizeof(u16), stream);
  hipMemsetAsync(HC, 0, 460800*sizeof(float), stream);
  k_pack<<<(3600*928+255)/256, 256, 0, stream>>>(Wih1, Wp,  900, 928, 3600*928, dflag);
  k_pack<<<(3600*480+255)/256, 256, 0, stream>>>(Whh1, Whp, 450, 480, 3600*480, dflag);
  k_mgemm<<<dim3(15,10,2), 256, 0, stream>>>(
      Y0bf, 928, 0, Wp, 928, (size_t)1800*928,
      bih1, bhh1, 1800, dflag, nullptr, nullptr,
      Gb, 1, 2304000, 1800, 29);
  for (int s = 0; s < 5; ++s){
    k_mgemm<<<dim3(15,2,2), 256, 0, stream>>>(
        Hbf, 480, (size_t)256*480, Whp, 480, (size_t)1800*480,
        nullptr, nullptr, 0, dflag,
        Gb + (size_t)s*460800, Gb + (size_t)(9-s)*460800,
        GT, 0, 460800, 1800, 15);
    k_cell<<<900, 256, 0, stream>>>(GT, HC, Hbf, nullptr, Y1, HF, s, 1);
  }

  k_attn<<<256, 256, 0, stream>>>(Y1, HF, CTX);
  k_gemm<<<dim3(1,256), 256, 1800*4, stream>>>(CTX, outw, 0, outb, nullptr, 0,
                                               dflag, RELb, 1800, 100);
  k_grad<<<256, 128, 0, stream>>>(support, supneg, normv, RELb, dflag, RELQ, NORMQ);
  k_score<<<dim3(256,3), 192, 0, stream>>>(query, negat, RELQ, NORMQ, dflag, d_out);
}